// Round 20
// baseline (11310.842 us; speedup 1.0000x reference)
//
#include <hip/hip_runtime.h>

#define Bb 256
#define Ll 1024
#define CH 16

typedef _Float16 h2v __attribute__((ext_vector_type(2)));

__device__ __forceinline__ unsigned pack_h2(float a, float b) {
  h2v v; v[0] = (_Float16)a; v[1] = (_Float16)b;
  return __builtin_bit_cast(unsigned, v);
}
__device__ __forceinline__ float dot2(unsigned w, unsigned x, float acc) {
#if defined(__has_builtin) && __has_builtin(__builtin_amdgcn_fdot2)
  return __builtin_amdgcn_fdot2(__builtin_bit_cast(h2v, w),
                                __builtin_bit_cast(h2v, x), acc, false);
#else
  h2v wv = __builtin_bit_cast(h2v, w), xv = __builtin_bit_cast(h2v, x);
  acc = fmaf((float)wv[0], (float)xv[0], acc);
  return fmaf((float)wv[1], (float)xv[1], acc);
#endif
}
__device__ __forceinline__ float dppadd1(float v) {   // + lane^1
  int s = __builtin_amdgcn_mov_dpp(__builtin_bit_cast(int, v), 0xB1, 0xF, 0xF, true);
  return v + __builtin_bit_cast(float, s);
}
__device__ __forceinline__ float dppadd2(float v) {   // + lane^2
  int s = __builtin_amdgcn_mov_dpp(__builtin_bit_cast(int, v), 0x4E, 0xF, 0xF, true);
  return v + __builtin_bit_cast(float, s);
}
__device__ __forceinline__ float qsum(float a0, float a1) {
  return dppadd2(dppadd1(a0 + a1));   // quad-uniform sum
}
__device__ __forceinline__ float fast_tanh(float x) {
  float e = __expf(2.0f * x);
  return 1.0f - 2.0f / (e + 1.0f);
}
__device__ __forceinline__ float fast_sigmoid(float x) {
  return 1.0f / (1.0f + __expf(-x));
}

// 32-wide K-slice matvec (r12/r19-verified)
__device__ __forceinline__ float mv16(const unsigned* __restrict__ w,
                                      const unsigned* __restrict__ v, int q0) {
  float a0 = 0.0f, a1 = 0.0f;
#pragma unroll
  for (int c = 0; c < 4; ++c) {
    const uint4 hv = *(const uint4*)&v[q0 + 4 * c];
    a0 = dot2(w[4*c+0], hv.x, a0); a1 = dot2(w[4*c+1], hv.y, a1);
    a0 = dot2(w[4*c+2], hv.z, a0); a1 = dot2(w[4*c+3], hv.w, a1);
  }
  return qsum(a0, a1);
}
// matvec with LDS-resident XOR-swizzled weight row (r12/r19-verified)
__device__ __forceinline__ float giq(const unsigned* __restrict__ wrow,
                                     const unsigned* __restrict__ xe,
                                     int q0, int swi) {
  float g0 = 0.0f, g1 = 0.0f;
#pragma unroll
  for (int c = 0; c < 4; ++c) {
    const uint4 xv = *(const uint4*)&xe[q0 + 4 * c];
    const uint4 w4 = *(const uint4*)&wrow[(q0 + 4 * c) ^ swi];
    g0 = dot2(w4.x, xv.x, g0); g1 = dot2(w4.y, xv.y, g1);
    g0 = dot2(w4.z, xv.z, g0); g1 = dot2(w4.w, xv.w, g1);
  }
  return qsum(g0, g1);
}

// ---- prepass: M = W1·W2 (16384 f32), c = W1·b2 (128 f32) into ws ----
__global__ __launch_bounds__(256) void k_prep(
    const float* __restrict__ W1, const float* __restrict__ W2,
    const float* __restrict__ b2, float* __restrict__ ws)
{
  const int idx = blockIdx.x * 256 + threadIdx.x;
  if (idx < 16384) {
    const int i = idx >> 7, j = idx & 127;
    float s = 0.f;
    for (int k = 0; k < 128; ++k) s = fmaf(W1[i * 128 + k], W2[k * 128 + j], s);
    ws[idx] = s;
  } else if (idx < 16512) {
    const int i = idx - 16384;
    float s = 0.f;
    for (int k = 0; k < 128; ++k) s = fmaf(W1[i * 128 + k], b2[k], s);
    ws[idx] = s;
  }
}

// 1024 threads = 2 batch rows per WG (waves 0-7 row 0, waves 8-15 row 1),
// identical code per row (uniform regalloc), shared Wih/W2 LDS images.
// Per row: r19's 6-phase v-chain schedule, 4-way K-split.
__global__ __launch_bounds__(1024, 1) void k_fused(
    const float* __restrict__ x, const float* __restrict__ dtp,
    const int* __restrict__ mask,
    const float* __restrict__ Wx, const float* __restrict__ bx,
    const float* __restrict__ W1, const float* __restrict__ b1,
    const float* __restrict__ W2, const float* __restrict__ b2,
    const float* __restrict__ Wih, const float* __restrict__ bih,
    const float* __restrict__ Whh, const float* __restrict__ bhh,
    const float* __restrict__ lng, const float* __restrict__ lnb,
    const float* __restrict__ Whd, const float* __restrict__ bhp,
    const float* __restrict__ ws,
    float* __restrict__ out)
{
  const float* Mf = ws;
  const float* cf = ws + 16384;

  const int tid = threadIdx.x;
  const int lane = tid & 63;
  const int row = tid >> 9;           // 0 or 1
  const int rtid = tid & 511;
  const int wr = (tid >> 6) & 7;      // row-local wave 0..7
  const int jl = lane >> 2;           // 0..15
  const int ks = lane & 3;            // 0..3
  const int j = (wr << 4) + jl;       // 0..127
  const int q0 = ks << 4;
  const int q0x = ks << 3;
  const int swi = (j & 15) << 2;
  const int b = blockIdx.x * 2 + row; // batch row

  __shared__ int act_lds[Ll];                               // 4 KB
  __shared__ __align__(16) unsigned wih_lds[3 * 128 * 64];  // 96 KB (shared)
  __shared__ __align__(16) unsigned w2_lds[128 * 64];       // 32 KB (shared)
  __shared__ __align__(16) unsigned x16[2][2][CH * 32];     // 8 KB
  __shared__ __align__(16) unsigned xe16[2][64];
  __shared__ __align__(16) unsigned ubuf[2][2][64];
  __shared__ __align__(16) unsigned usumb[2][64];
  __shared__ __align__(16) unsigned fb16[2][64];
  __shared__ __align__(16) unsigned h16[2][2][64];
  __shared__ float dt_ch[2][2][CH];
  __shared__ int   m_ch[2][2][CH];
  __shared__ float red_lds[2][48];
  __shared__ float cc_lds[2];

  // ---- act prepass (coalesced, all 1024 threads) ----
  for (int t0 = tid; t0 < Ll; t0 += 1024) {
    int a = 0;
#pragma unroll 8
    for (int bb = 0; bb < Bb; ++bb) a |= mask[(size_t)bb * Ll + t0];
    act_lds[t0] = a;
  }
  // ---- Wih -> LDS f16 pairs, XOR-swizzled (shared) ----
  for (int idx = tid; idx < 3 * 128 * 64; idx += 1024) {
    const int r = idx >> 6, w = idx & 63;
    wih_lds[(r << 6) | (w ^ ((r & 15) << 2))] =
        pack_h2(Wih[(size_t)r * 128 + 2 * w], Wih[(size_t)r * 128 + 2 * w + 1]);
  }
  // ---- W2 -> LDS f16 pairs, same swizzle (shared) ----
  for (int idx = tid; idx < 128 * 64; idx += 1024) {
    const int r = idx >> 6, w = idx & 63;
    w2_lds[(r << 6) | (w ^ ((r & 15) << 2))] =
        pack_h2(W2[(size_t)r * 128 + 2 * w], W2[(size_t)r * 128 + 2 * w + 1]);
  }
  if (tid == 0) {
    float s1 = 0.f, s0 = 0.f;
    for (int i = 0; i < 128; ++i) { s1 += lng[i] * Whd[i]; s0 += lnb[i] * Whd[i]; }
    cc_lds[0] = s1; cc_lds[1] = s0 + bhp[0];
  }
  // ---- chunk 0 (steps 0..15) per row ----
  {
    const int sl = rtid >> 5, part = rtid & 31;
    const float2 a = *(const float2*)(x + ((size_t)b * Ll + sl) * 64 + part * 2);
    x16[row][0][sl * 32 + part] = pack_h2(a.x, a.y);
    if (rtid < CH) dt_ch[row][0][rtid] = dtp[(size_t)b * Ll + rtid];
    else if (rtid < 2 * CH) m_ch[row][0][rtid - CH] = mask[(size_t)b * Ll + (rtid - CH)];
  }
  // ---- register-stationary weights (88 u32): W1, M, Whh(x3), Wx ----
  unsigned w1h[16], mh[16], whr[16], whz[16], whn[16], wxh[8];
#pragma unroll
  for (int ii = 0; ii < 8; ++ii) {
    float4 a4;
    a4 = *(const float4*)&W1[(size_t)j * 128 + (ks << 5) + 4 * ii];
    w1h[2*ii] = pack_h2(a4.x, a4.y); w1h[2*ii+1] = pack_h2(a4.z, a4.w);
    a4 = *(const float4*)&Mf[(size_t)j * 128 + (ks << 5) + 4 * ii];
    mh[2*ii] = pack_h2(a4.x, a4.y); mh[2*ii+1] = pack_h2(a4.z, a4.w);
    a4 = *(const float4*)&Whh[(size_t)j * 128 + (ks << 5) + 4 * ii];
    whr[2*ii] = pack_h2(a4.x, a4.y); whr[2*ii+1] = pack_h2(a4.z, a4.w);
    a4 = *(const float4*)&Whh[(size_t)(128 + j) * 128 + (ks << 5) + 4 * ii];
    whz[2*ii] = pack_h2(a4.x, a4.y); whz[2*ii+1] = pack_h2(a4.z, a4.w);
    a4 = *(const float4*)&Whh[(size_t)(256 + j) * 128 + (ks << 5) + 4 * ii];
    whn[2*ii] = pack_h2(a4.x, a4.y); whn[2*ii+1] = pack_h2(a4.z, a4.w);
  }
#pragma unroll
  for (int ii = 0; ii < 4; ++ii) {
    const float4 a4 = *(const float4*)&Wx[(size_t)j * 64 + (ks << 4) + 4 * ii];
    wxh[2*ii] = pack_h2(a4.x, a4.y); wxh[2*ii+1] = pack_h2(a4.z, a4.w);
  }
  const float bxj = bx[j], b1j = b1[j], b2j = b2[j], cj = cf[j];
  const float bir = bih[j], biz = bih[128 + j], bin_ = bih[256 + j];
  const float bhr = bhh[j], bhz = bhh[128 + j], bhn = bhh[256 + j];
  const float gw = lng[j] * Whd[j];

  if (rtid < 64) { h16[row][0][rtid] = 0u; h16[row][1][rtid] = 0u; }
  float hreg = 0.f;
  float gicr = 0.f, gicz = 0.f, gicn = 0.f;
  float gnr = 0.f, gnz = 0.f, gnn = 0.f;
  float accb = 0.f, cntb = 0.f;               // rtid==0 per row
  int mreg = 0;
  float2 rx0 = {0, 0}; float rdt = 0.f; int rmk = 0;
  __syncthreads();

  // ---- prologue: xe(0), then gi(0), per row ----
  {
    float p0 = 0.f, p1 = 0.f;
#pragma unroll
    for (int c = 0; c < 2; ++c) {
      const uint4 xv = *(const uint4*)&x16[row][0][q0x + 4 * c];
      p0 = dot2(wxh[4*c+0], xv.x, p0); p1 = dot2(wxh[4*c+1], xv.y, p1);
      p0 = dot2(wxh[4*c+2], xv.z, p0); p1 = dot2(wxh[4*c+3], xv.w, p1);
    }
    const float xev = fmaxf(qsum(p0, p1) + bxj, 0.f);
    if (ks == 0) ((_Float16*)xe16[row])[j] = (_Float16)xev;
  }
  __syncthreads();
  gicr = giq(&wih_lds[j << 6], xe16[row], q0, swi) + bir;
  gicz = giq(&wih_lds[(128 + j) << 6], xe16[row], q0, swi) + biz;
  gicn = giq(&wih_lds[(256 + j) << 6], xe16[row], q0, swi) + bin_;
  __syncthreads();

#pragma unroll 1
  for (int t = 0; t < Ll; ++t) {
    const int cb = (t >> 4) & 1, tc = t & 15;
    const float sv = dt_ch[row][cb][tc] * (float)m_ch[row][cb][tc] * 0.25f;
    const unsigned* hb = h16[row][t & 1];
    const int refill = (tc == 8) && ((t >> 4) < 63);

    float v, usum;

    // ===== P1: v = W1·h ; u0 ; xe(t+1) ; logit(t-1) ; refill-issue =====
    {
      if (refill) {
        const int sl = rtid >> 5, part = rtid & 31;
        rx0 = *(const float2*)(x + ((size_t)b * Ll + ((t >> 4) + 1) * CH + sl) * 64 + part * 2);
        if (rtid < CH) rdt = dtp[(size_t)b * Ll + ((t >> 4) + 1) * CH + rtid];
        else if (rtid < 2 * CH) rmk = mask[(size_t)b * Ll + ((t >> 4) + 1) * CH + (rtid - CH)];
      }
      v = mv16(w1h, hb, q0);
      const float u0 = fast_tanh(v + b1j);
      usum = u0;
      if (ks == 0) ((_Float16*)ubuf[row][0])[j] = (_Float16)u0;
      if (t + 1 < Ll) {
        const int nb2 = ((t + 1) >> 4) & 1, ns = (t + 1) & 15;
        float p0 = 0.f, p1 = 0.f;
#pragma unroll
        for (int c = 0; c < 2; ++c) {
          const uint4 xv = *(const uint4*)&x16[row][nb2][ns * 32 + q0x + 4 * c];
          p0 = dot2(wxh[4*c+0], xv.x, p0); p1 = dot2(wxh[4*c+1], xv.y, p1);
          p0 = dot2(wxh[4*c+2], xv.z, p0); p1 = dot2(wxh[4*c+3], xv.w, p1);
        }
        const float xev = fmaxf(qsum(p0, p1) + bxj, 0.f);
        if (ks == 0) ((_Float16*)xe16[row])[j] = (_Float16)xev;
      }
      if (rtid == 0 && t > 0) {
        float S1 = 0.f, S2 = 0.f, SD = 0.f;
#pragma unroll
        for (int q = 0; q < 16; ++q) {
          S1 += red_lds[row][q * 3 + 0]; S2 += red_lds[row][q * 3 + 1]; SD += red_lds[row][q * 3 + 2];
        }
        if (mreg) {
          const float mu = S1 * (1.0f / 128.0f);
          const float var = S2 * (1.0f / 128.0f) - mu * mu;
          const float rstd = rsqrtf(var + 1e-5f);
          accb += rstd * (SD - mu * cc_lds[0]) + cc_lds[1];
          cntb += 1.f;
        }
      }
    }
    __syncthreads();                       // B1

    // ===== P2: v += sv(M·u0 + c) ; u1 ; gi_r(t+1) =====
    {
      const float t2 = mv16(mh, ubuf[row][0], q0);
      v = fmaf(sv, t2 + cj, v);
      const float u1 = fast_tanh(v + b1j);
      usum += u1;
      if (ks == 0) ((_Float16*)ubuf[row][1])[j] = (_Float16)u1;
      gnr = giq(&wih_lds[j << 6], xe16[row], q0, swi) + bir;
    }
    __syncthreads();                       // B2

    // ===== P3: v += sv(M·u1 + c) ; u2 ; gi_z(t+1) =====
    {
      const float t2 = mv16(mh, ubuf[row][1], q0);
      v = fmaf(sv, t2 + cj, v);
      const float u2 = fast_tanh(v + b1j);
      usum += u2;
      if (ks == 0) ((_Float16*)ubuf[row][0])[j] = (_Float16)u2;
      gnz = giq(&wih_lds[(128 + j) << 6], xe16[row], q0, swi) + biz;
    }
    __syncthreads();                       // B3

    // ===== P4: v += sv(M·u2 + c) ; u3 ; usum ; gi_n(t+1) =====
    {
      const float t2 = mv16(mh, ubuf[row][0], q0);
      v = fmaf(sv, t2 + cj, v);
      const float u3 = fast_tanh(v + b1j);
      usum += u3;
      if (ks == 0) ((_Float16*)usumb[row])[j] = (_Float16)usum;
      gnn = giq(&wih_lds[(256 + j) << 6], xe16[row], q0, swi) + bin_;
    }
    __syncthreads();                       // B4

    // ===== P5: h_fin = h0 + sv·W2·usum + 4sv·b2 ; refill-write =====
    float hf;
    {
      const float k2 = giq(&w2_lds[j << 6], usumb[row], q0, swi);
      hf = hreg + sv * k2 + 4.f * sv * b2j;
      if (ks == 0) ((_Float16*)fb16[row])[j] = (_Float16)hf;
      if (refill) {
        const int nb = ((t >> 4) + 1) & 1;
        const int sl = rtid >> 5, part = rtid & 31;
        x16[row][nb][sl * 32 + part] = pack_h2(rx0.x, rx0.y);
        if (rtid < CH) dt_ch[row][nb][rtid] = rdt;
        else if (rtid < 2 * CH) m_ch[row][nb][rtid - CH] = rmk;
      }
    }
    __syncthreads();                       // B5

    // ===== P6: GRU gates on h_fin ; h_new ; LN partials =====
    {
      const float pr = mv16(whr, fb16[row], q0) + bhr;
      const float pz = mv16(whz, fb16[row], q0) + bhz;
      const float pn = mv16(whn, fb16[row], q0) + bhn;
      const float rr = fast_sigmoid(gicr + pr);
      const float zz = fast_sigmoid(gicz + pz);
      const float nn = fast_tanh(gicn + rr * pn);
      const float hg = (1.f - zz) * nn + zz * hf;
      hreg = act_lds[t] ? hg : hf;
      if (ks == 0) ((_Float16*)h16[row][(t + 1) & 1])[j] = (_Float16)hreg;
      float s1 = hreg, s2 = hreg * hreg, sd = hreg * gw;
#pragma unroll
      for (int o = 4; o <= 16; o <<= 1) {
        s1 += __shfl_xor(s1, o); s2 += __shfl_xor(s2, o); sd += __shfl_xor(sd, o);
      }
      if ((lane & 31) == 0) {
        const int slot = (wr << 1) | (lane >> 5);
        red_lds[row][slot * 3 + 0] = s1; red_lds[row][slot * 3 + 1] = s2; red_lds[row][slot * 3 + 2] = sd;
      }
      if (rtid == 0) mreg = m_ch[row][cb][tc];
      gicr = gnr; gicz = gnz; gicn = gnn;
    }
    __syncthreads();                       // B6
  }

  // ---- epilogue: logit for t=1023, per row ----
  if (rtid == 0) {
    float S1 = 0.f, S2 = 0.f, SD = 0.f;
#pragma unroll
    for (int q = 0; q < 16; ++q) {
      S1 += red_lds[row][q * 3 + 0]; S2 += red_lds[row][q * 3 + 1]; SD += red_lds[row][q * 3 + 2];
    }
    if (mreg) {
      const float mu = S1 * (1.0f / 128.0f);
      const float var = S2 * (1.0f / 128.0f) - mu * mu;
      const float rstd = rsqrtf(var + 1e-5f);
      accb += rstd * (SD - mu * cc_lds[0]) + cc_lds[1];
      cntb += 1.f;
    }
    out[b] = accb / fmaxf(cntb, 1.f);
  }
}

// ---------------- host ----------------
extern "C" void kernel_launch(void* const* d_in, const int* in_sizes, int n_in,
                              void* d_out, int out_size, void* d_ws, size_t ws_size,
                              hipStream_t stream) {
  const float* x    = (const float*)d_in[0];
  const float* dt   = (const float*)d_in[1];
  const int*   mask = (const int*)d_in[2];
  const float* Wx   = (const float*)d_in[3];
  const float* bx   = (const float*)d_in[4];
  const float* W1   = (const float*)d_in[5];
  const float* b1   = (const float*)d_in[6];
  const float* W2   = (const float*)d_in[7];
  const float* b2   = (const float*)d_in[8];
  const float* Wih  = (const float*)d_in[9];
  const float* bih  = (const float*)d_in[10];
  const float* Whh  = (const float*)d_in[11];
  const float* bhh  = (const float*)d_in[12];
  const float* lng  = (const float*)d_in[13];
  const float* lnb  = (const float*)d_in[14];
  const float* Wh   = (const float*)d_in[15];
  const float* bh   = (const float*)d_in[16];
  float* ws = (float*)d_ws;   // needs 16512 floats = 64.5 KB
  float* out = (float*)d_out;

  k_prep<<<dim3(65), dim3(256), 0, stream>>>(W1, W2, b2, ws);
  k_fused<<<dim3(Bb / 2), dim3(1024), 0, stream>>>(
      x, dt, mask, Wx, bx, W1, b1, W2, b2, Wih, bih, Whh, bhh,
      lng, lnb, Wh, bh, ws, out);
}

// Round 21
// 2770.631 us; speedup vs baseline: 4.0824x; 4.0824x over previous
//
#include <hip/hip_runtime.h>

#define Bb 256
#define Ll 1024
#define CH 32

typedef _Float16 h2v __attribute__((ext_vector_type(2)));

__device__ __forceinline__ unsigned pack_h2(float a, float b) {
  h2v v; v[0] = (_Float16)a; v[1] = (_Float16)b;
  return __builtin_bit_cast(unsigned, v);
}
__device__ __forceinline__ float dot2(unsigned w, unsigned x, float acc) {
#if defined(__has_builtin) && __has_builtin(__builtin_amdgcn_fdot2)
  return __builtin_amdgcn_fdot2(__builtin_bit_cast(h2v, w),
                                __builtin_bit_cast(h2v, x), acc, false);
#else
  h2v wv = __builtin_bit_cast(h2v, w), xv = __builtin_bit_cast(h2v, x);
  acc = fmaf((float)wv[0], (float)xv[0], acc);
  return fmaf((float)wv[1], (float)xv[1], acc);
#endif
}
__device__ __forceinline__ float dppadd1(float v) {   // + lane^1
  int s = __builtin_amdgcn_mov_dpp(__builtin_bit_cast(int, v), 0xB1, 0xF, 0xF, true);
  return v + __builtin_bit_cast(float, s);
}
__device__ __forceinline__ float dppadd2(float v) {   // + lane^2
  int s = __builtin_amdgcn_mov_dpp(__builtin_bit_cast(int, v), 0x4E, 0xF, 0xF, true);
  return v + __builtin_bit_cast(float, s);
}
__device__ __forceinline__ float qsum(float a0, float a1) {
  return dppadd2(dppadd1(a0 + a1));   // sum across the 4-lane quad (quad-uniform)
}
__device__ __forceinline__ float fast_tanh(float x) {
  float e = __expf(2.0f * x);
  return 1.0f - 2.0f / (e + 1.0f);
}
__device__ __forceinline__ float fast_sigmoid(float x) {
  return 1.0f / (1.0f + __expf(-x));
}

// 32-wide K-slice matvec: 16 dot2, 2 chains, quad reduce (result quad-uniform)
__device__ __forceinline__ float mv16(const unsigned* __restrict__ w,
                                      const unsigned* __restrict__ v, int q0) {
  float a0 = 0.0f, a1 = 0.0f;
#pragma unroll
  for (int c = 0; c < 4; ++c) {
    const uint4 hv = *(const uint4*)&v[q0 + 4 * c];
    a0 = dot2(w[4*c+0], hv.x, a0); a1 = dot2(w[4*c+1], hv.y, a1);
    a0 = dot2(w[4*c+2], hv.z, a0); a1 = dot2(w[4*c+3], hv.w, a1);
  }
  return qsum(a0, a1);
}
// matvec with LDS-resident XOR-swizzled weight row (r12-verified)
__device__ __forceinline__ float giq(const unsigned* __restrict__ wrow,
                                     const unsigned* __restrict__ xe,
                                     int q0, int swi) {
  float g0 = 0.0f, g1 = 0.0f;
#pragma unroll
  for (int c = 0; c < 4; ++c) {
    const uint4 xv = *(const uint4*)&xe[q0 + 4 * c];
    const uint4 w4 = *(const uint4*)&wrow[(q0 + 4 * c) ^ swi];
    g0 = dot2(w4.x, xv.x, g0); g1 = dot2(w4.y, xv.y, g1);
    g0 = dot2(w4.z, xv.z, g0); g1 = dot2(w4.w, xv.w, g1);
  }
  return qsum(g0, g1);
}

// ---- prepass: M = W1·W2 (16384 f32), c = W1·b2 (128 f32) into ws ----
__global__ __launch_bounds__(256) void k_prep(
    const float* __restrict__ W1, const float* __restrict__ W2,
    const float* __restrict__ b2, float* __restrict__ ws)
{
  const int idx = blockIdx.x * 256 + threadIdx.x;
  if (idx < 16384) {
    const int i = idx >> 7, j = idx & 127;
    float s = 0.f;
    for (int k = 0; k < 128; ++k) s = fmaf(W1[i * 128 + k], W2[k * 128 + j], s);
    ws[idx] = s;
  } else if (idx < 16512) {
    const int i = idx - 16384;
    float s = 0.f;
    for (int k = 0; k < 128; ++k) s = fmaf(W1[i * 128 + k], b2[k], s);
    ws[idx] = s;
  }
}

// One WG (512 thr, 8 waves) per batch row; r12 mapping: j = wv*16 + (lane>>2),
// ks = lane&3 (32-wide K-slice). 6 phases/step via v-chain algebra.
__global__ __launch_bounds__(512, 1) void k_fused(
    const float* __restrict__ x, const float* __restrict__ dtp,
    const int* __restrict__ mask,
    const float* __restrict__ Wx, const float* __restrict__ bx,
    const float* __restrict__ W1, const float* __restrict__ b1,
    const float* __restrict__ W2, const float* __restrict__ b2,
    const float* __restrict__ Wih, const float* __restrict__ bih,
    const float* __restrict__ Whh, const float* __restrict__ bhh,
    const float* __restrict__ lng, const float* __restrict__ lnb,
    const float* __restrict__ Whd, const float* __restrict__ bhp,
    const float* __restrict__ ws,
    float* __restrict__ out)
{
  const float* Mf = ws;
  const float* cf = ws + 16384;

  const int b = blockIdx.x;
  const int tid = threadIdx.x;
  const int lane = tid & 63;
  const int wv = tid >> 6;            // 0..7
  const int jl = lane >> 2;           // 0..15
  const int ks = lane & 3;            // 0..3
  const int j = (wv << 4) + jl;       // 0..127
  const int q0 = ks << 4;             // u32 base in 64-u32 (K=128) arrays
  const int q0x = ks << 3;            // u32 base in 32-u32 (F=64) rows
  const int swi = (j & 15) << 2;

  __shared__ int act_lds[Ll];                               // 4 KB
  __shared__ __align__(16) unsigned wih_lds[3 * 128 * 64];  // 96 KB, swizzled
  __shared__ __align__(16) unsigned w2_lds[128 * 64];       // 32 KB, swizzled
  __shared__ __align__(16) unsigned x16[2][CH * 32];        // 8 KB (dbuf)
  __shared__ __align__(16) unsigned xe16[64];
  __shared__ __align__(16) unsigned ubuf[2][64];
  __shared__ __align__(16) unsigned usumb[64];
  __shared__ __align__(16) unsigned fb16[64];
  __shared__ __align__(16) unsigned h16[2][64];
  __shared__ float dt_ch[2][CH];
  __shared__ int   m_ch[2][CH];
  __shared__ float red_lds[48];
  __shared__ float cc_lds[2];

  // ---- act prepass (coalesced) ----
  for (int t0 = tid; t0 < Ll; t0 += 512) {
    int a = 0;
#pragma unroll 8
    for (int bb = 0; bb < Bb; ++bb) a |= mask[(size_t)bb * Ll + t0];
    act_lds[t0] = a;
  }
  // ---- Wih -> LDS f16 pairs, XOR-swizzled (r12-verified) ----
  for (int idx = tid; idx < 3 * 128 * 64; idx += 512) {
    const int r = idx >> 6, w = idx & 63;
    wih_lds[(r << 6) | (w ^ ((r & 15) << 2))] =
        pack_h2(Wih[(size_t)r * 128 + 2 * w], Wih[(size_t)r * 128 + 2 * w + 1]);
  }
  // ---- W2 -> LDS f16 pairs, same swizzle ----
  for (int idx = tid; idx < 128 * 64; idx += 512) {
    const int r = idx >> 6, w = idx & 63;
    w2_lds[(r << 6) | (w ^ ((r & 15) << 2))] =
        pack_h2(W2[(size_t)r * 128 + 2 * w], W2[(size_t)r * 128 + 2 * w + 1]);
  }
  if (tid == 0) {
    float s1 = 0.f, s0 = 0.f;
    for (int i = 0; i < 128; ++i) { s1 += lng[i] * Whd[i]; s0 += lnb[i] * Whd[i]; }
    cc_lds[0] = s1; cc_lds[1] = s0 + bhp[0];
  }
  // ---- chunk 0 (steps 0..31) ----
  {
    const int sl = tid >> 4, part = tid & 15;
    const float4 a = *(const float4*)(x + ((size_t)b * Ll + sl) * 64 + part * 4);
    x16[0][sl * 32 + part * 2 + 0] = pack_h2(a.x, a.y);
    x16[0][sl * 32 + part * 2 + 1] = pack_h2(a.z, a.w);
    if (tid < CH) dt_ch[0][tid] = dtp[(size_t)b * Ll + tid];
    else if (tid < 2 * CH) m_ch[0][tid - CH] = mask[(size_t)b * Ll + (tid - CH)];
  }
  // ---- register-stationary weights (88 u32): W1, M, Whh(x3), Wx ----
  unsigned w1h[16], mh[16], whr[16], whz[16], whn[16], wxh[8];
#pragma unroll
  for (int ii = 0; ii < 8; ++ii) {
    float4 a4;
    a4 = *(const float4*)&W1[(size_t)j * 128 + (ks << 5) + 4 * ii];
    w1h[2*ii] = pack_h2(a4.x, a4.y); w1h[2*ii+1] = pack_h2(a4.z, a4.w);
    a4 = *(const float4*)&Mf[(size_t)j * 128 + (ks << 5) + 4 * ii];
    mh[2*ii] = pack_h2(a4.x, a4.y); mh[2*ii+1] = pack_h2(a4.z, a4.w);
    a4 = *(const float4*)&Whh[(size_t)j * 128 + (ks << 5) + 4 * ii];
    whr[2*ii] = pack_h2(a4.x, a4.y); whr[2*ii+1] = pack_h2(a4.z, a4.w);
    a4 = *(const float4*)&Whh[(size_t)(128 + j) * 128 + (ks << 5) + 4 * ii];
    whz[2*ii] = pack_h2(a4.x, a4.y); whz[2*ii+1] = pack_h2(a4.z, a4.w);
    a4 = *(const float4*)&Whh[(size_t)(256 + j) * 128 + (ks << 5) + 4 * ii];
    whn[2*ii] = pack_h2(a4.x, a4.y); whn[2*ii+1] = pack_h2(a4.z, a4.w);
  }
#pragma unroll
  for (int ii = 0; ii < 4; ++ii) {
    const float4 a4 = *(const float4*)&Wx[(size_t)j * 64 + (ks << 4) + 4 * ii];
    wxh[2*ii] = pack_h2(a4.x, a4.y); wxh[2*ii+1] = pack_h2(a4.z, a4.w);
  }
  const float bxj = bx[j], b1j = b1[j], b2j = b2[j], cj = cf[j];
  const float bir = bih[j], biz = bih[128 + j], bin_ = bih[256 + j];
  const float bhr = bhh[j], bhz = bhh[128 + j], bhn = bhh[256 + j];
  const float gw = lng[j] * Whd[j];

  if (tid < 64) { h16[0][tid] = 0u; h16[1][tid] = 0u; }
  float hreg = 0.f;
  float gicr = 0.f, gicz = 0.f, gicn = 0.f;   // gi(t)
  float gnr = 0.f, gnz = 0.f, gnn = 0.f;      // gi(t+1)
  float accb = 0.f, cntb = 0.f;               // tid==0
  int mreg = 0;
  float4 rx0 = {0,0,0,0}; float rdt = 0.f; int rmk = 0;   // refill hold
  __syncthreads();

  // ---- prologue: xe(0), then gi(0) ----
  {
    float p0 = 0.f, p1 = 0.f;
#pragma unroll
    for (int c = 0; c < 2; ++c) {
      const uint4 xv = *(const uint4*)&x16[0][q0x + 4 * c];
      p0 = dot2(wxh[4*c+0], xv.x, p0); p1 = dot2(wxh[4*c+1], xv.y, p1);
      p0 = dot2(wxh[4*c+2], xv.z, p0); p1 = dot2(wxh[4*c+3], xv.w, p1);
    }
    const float xev = fmaxf(qsum(p0, p1) + bxj, 0.f);
    if (ks == 0) ((_Float16*)xe16)[j] = (_Float16)xev;
  }
  __syncthreads();
  gicr = giq(&wih_lds[j << 6], xe16, q0, swi) + bir;
  gicz = giq(&wih_lds[(128 + j) << 6], xe16, q0, swi) + biz;
  gicn = giq(&wih_lds[(256 + j) << 6], xe16, q0, swi) + bin_;
  __syncthreads();

#pragma unroll 1
  for (int t = 0; t < Ll; ++t) {
    const int cb = (t >> 5) & 1, tc = t & 31;
    const float sv = dt_ch[cb][tc] * (float)m_ch[cb][tc] * 0.25f;
    const unsigned* hb = h16[t & 1];
    const int refill = (tc == 16) && ((t >> 5) < 31);

    float v, usum;

    // ===== P1: v = W1·h ; u0 ; xe(t+1) ; logit(t-1) ; refill-issue =====
    {
      if (refill) {
        const int sl = tid >> 4, part = tid & 15;
        rx0 = *(const float4*)(x + ((size_t)b * Ll + ((t >> 5) + 1) * 32 + sl) * 64 + part * 4);
        if (tid < CH) rdt = dtp[(size_t)b * Ll + ((t >> 5) + 1) * 32 + tid];
        else if (tid < 2 * CH) rmk = mask[(size_t)b * Ll + ((t >> 5) + 1) * 32 + (tid - CH)];
      }
      v = mv16(w1h, hb, q0);
      const float u0 = fast_tanh(v + b1j);
      usum = u0;
      if (ks == 0) ((_Float16*)ubuf[0])[j] = (_Float16)u0;
      if (t + 1 < Ll) {
        const int nb2 = ((t + 1) >> 5) & 1, ns = (t + 1) & 31;
        float p0 = 0.f, p1 = 0.f;
#pragma unroll
        for (int c = 0; c < 2; ++c) {
          const uint4 xv = *(const uint4*)&x16[nb2][ns * 32 + q0x + 4 * c];
          p0 = dot2(wxh[4*c+0], xv.x, p0); p1 = dot2(wxh[4*c+1], xv.y, p1);
          p0 = dot2(wxh[4*c+2], xv.z, p0); p1 = dot2(wxh[4*c+3], xv.w, p1);
        }
        const float xev = fmaxf(qsum(p0, p1) + bxj, 0.f);
        if (ks == 0) ((_Float16*)xe16)[j] = (_Float16)xev;
      }
      if (tid == 0 && t > 0) {
        float S1 = 0.f, S2 = 0.f, SD = 0.f;
#pragma unroll
        for (int q = 0; q < 16; ++q) {
          S1 += red_lds[q * 3 + 0]; S2 += red_lds[q * 3 + 1]; SD += red_lds[q * 3 + 2];
        }
        if (mreg) {
          const float mu = S1 * (1.0f / 128.0f);
          const float var = S2 * (1.0f / 128.0f) - mu * mu;
          const float rstd = rsqrtf(var + 1e-5f);
          accb += rstd * (SD - mu * cc_lds[0]) + cc_lds[1];
          cntb += 1.f;
        }
      }
    }
    __syncthreads();                       // B1

    // ===== P2: v += sv(M·u0 + c) ; u1 ; gi_r(t+1) =====
    {
      const float t2 = mv16(mh, ubuf[0], q0);
      v = fmaf(sv, t2 + cj, v);
      const float u1 = fast_tanh(v + b1j);
      usum += u1;
      if (ks == 0) ((_Float16*)ubuf[1])[j] = (_Float16)u1;
      gnr = giq(&wih_lds[j << 6], xe16, q0, swi) + bir;
    }
    __syncthreads();                       // B2

    // ===== P3: v += sv(M·u1 + c) ; u2 ; gi_z(t+1) =====
    {
      const float t2 = mv16(mh, ubuf[1], q0);
      v = fmaf(sv, t2 + cj, v);
      const float u2 = fast_tanh(v + b1j);
      usum += u2;
      if (ks == 0) ((_Float16*)ubuf[0])[j] = (_Float16)u2;
      gnz = giq(&wih_lds[(128 + j) << 6], xe16, q0, swi) + biz;
    }
    __syncthreads();                       // B3

    // ===== P4: v += sv(M·u2 + c) ; u3 ; usum ; gi_n(t+1) =====
    {
      const float t2 = mv16(mh, ubuf[0], q0);
      v = fmaf(sv, t2 + cj, v);
      const float u3 = fast_tanh(v + b1j);
      usum += u3;
      if (ks == 0) ((_Float16*)usumb)[j] = (_Float16)usum;
      gnn = giq(&wih_lds[(256 + j) << 6], xe16, q0, swi) + bin_;
    }
    __syncthreads();                       // B4

    // ===== P5: h_fin = h0 + sv·W2·usum + 4sv·b2 ; refill-write =====
    float hf;
    {
      const float k2 = giq(&w2_lds[j << 6], usumb, q0, swi);
      hf = hreg + sv * k2 + 4.f * sv * b2j;
      if (ks == 0) ((_Float16*)fb16)[j] = (_Float16)hf;
      if (refill) {
        const int nb = ((t >> 5) + 1) & 1;
        const int sl = tid >> 4, part = tid & 15;
        x16[nb][sl * 32 + part * 2 + 0] = pack_h2(rx0.x, rx0.y);
        x16[nb][sl * 32 + part * 2 + 1] = pack_h2(rx0.z, rx0.w);
        if (tid < CH) dt_ch[nb][tid] = rdt;
        else if (tid < 2 * CH) m_ch[nb][tid - CH] = rmk;
      }
    }
    __syncthreads();                       // B5

    // ===== P6: GRU gates on h_fin ; h_new ; LN partials =====
    {
      const float pr = mv16(whr, fb16, q0) + bhr;
      const float pz = mv16(whz, fb16, q0) + bhz;
      const float pn = mv16(whn, fb16, q0) + bhn;
      const float rr = fast_sigmoid(gicr + pr);
      const float zz = fast_sigmoid(gicz + pz);
      const float nn = fast_tanh(gicn + rr * pn);
      const float hg = (1.f - zz) * nn + zz * hf;
      hreg = act_lds[t] ? hg : hf;
      if (ks == 0) ((_Float16*)h16[(t + 1) & 1])[j] = (_Float16)hreg;
      // LN partials (quad-uniform h[j]): xor 4,8,16 -> 16 slots
      float s1 = hreg, s2 = hreg * hreg, sd = hreg * gw;
#pragma unroll
      for (int o = 4; o <= 16; o <<= 1) {
        s1 += __shfl_xor(s1, o); s2 += __shfl_xor(s2, o); sd += __shfl_xor(sd, o);
      }
      if ((lane & 31) == 0) {
        const int slot = (wv << 1) | (lane >> 5);
        red_lds[slot * 3 + 0] = s1; red_lds[slot * 3 + 1] = s2; red_lds[slot * 3 + 2] = sd;
      }
      if (tid == 0) mreg = m_ch[cb][tc];
      gicr = gnr; gicz = gnz; gicn = gnn;
    }
    __syncthreads();                       // B6
  }

  // ---- epilogue: logit for t=1023 ----
  if (tid == 0) {
    float S1 = 0.f, S2 = 0.f, SD = 0.f;
#pragma unroll
    for (int q = 0; q < 16; ++q) {
      S1 += red_lds[q * 3 + 0]; S2 += red_lds[q * 3 + 1]; SD += red_lds[q * 3 + 2];
    }
    if (mreg) {
      const float mu = S1 * (1.0f / 128.0f);
      const float var = S2 * (1.0f / 128.0f) - mu * mu;
      const float rstd = rsqrtf(var + 1e-5f);
      accb += rstd * (SD - mu * cc_lds[0]) + cc_lds[1];
      cntb += 1.f;
    }
    out[b] = accb / fmaxf(cntb, 1.f);
  }
}

// ---------------- host ----------------
extern "C" void kernel_launch(void* const* d_in, const int* in_sizes, int n_in,
                              void* d_out, int out_size, void* d_ws, size_t ws_size,
                              hipStream_t stream) {
  const float* x    = (const float*)d_in[0];
  const float* dt   = (const float*)d_in[1];
  const int*   mask = (const int*)d_in[2];
  const float* Wx   = (const float*)d_in[3];
  const float* bx   = (const float*)d_in[4];
  const float* W1   = (const float*)d_in[5];
  const float* b1   = (const float*)d_in[6];
  const float* W2   = (const float*)d_in[7];
  const float* b2   = (const float*)d_in[8];
  const float* Wih  = (const float*)d_in[9];
  const float* bih  = (const float*)d_in[10];
  const float* Whh  = (const float*)d_in[11];
  const float* bhh  = (const float*)d_in[12];
  const float* lng  = (const float*)d_in[13];
  const float* lnb  = (const float*)d_in[14];
  const float* Wh   = (const float*)d_in[15];
  const float* bh   = (const float*)d_in[16];
  float* ws = (float*)d_ws;   // needs 16512 floats = 64.5 KB
  float* out = (float*)d_out;

  k_prep<<<dim3(65), dim3(256), 0, stream>>>(W1, W2, b2, ws);
  k_fused<<<dim3(Bb), dim3(512), 0, stream>>>(
      x, dt, mask, Wx, bx, W1, b1, W2, b2, Wih, bih, Whh, bhh,
      lng, lnb, Wh, bh, ws, out);
}